// Round 1
// baseline (1685.424 us; speedup 1.0000x reference)
//
#include <hip/hip_runtime.h>

#define NN 100000
#define NE 1600000
#define ND 64
#define HD 128
#define NIN 129   // 2*ND + ED

// ---------------------------------------------------------------------------
// msg_kernel: per-edge MLP  m = W2 @ relu(W1 @ [x_src; x_dst; ea] + b1) + b2
// then atomic scatter-add into aggr[dst].
// 1024 threads = 16 waves / block; 1 block per CU (LDS-limited).
// Each wave processes 4 edges per iteration (amortizes weight reads 4x,
// enables b128 broadcast of the 4 edge-vectors).
// ---------------------------------------------------------------------------
__global__ __launch_bounds__(1024) void msg_kernel(
    const float* __restrict__ x, const int* __restrict__ ei,
    const float* __restrict__ ea, const float* __restrict__ W1,
    const float* __restrict__ b1, const float* __restrict__ W2,
    const float* __restrict__ b2, float* __restrict__ aggr)
{
    // w1p[k][j] = {W1[j][k], W1[j+64][k]}   (66048 B)
    __shared__ float2 w1p[NIN][ND];
    // w2t[k][j] = W2[j][k]                  (32768 B)
    __shared__ float  w2t[HD][ND];
    // per-wave edge vectors (and later h), interleaved x4 edges (33792 B)
    __shared__ float4 vbuf[16][132];
    // total LDS: 132608 B  (<= 160 KiB per workgroup on gfx950)

    const int tid  = threadIdx.x;
    const int lane = tid & 63;
    const int w    = tid >> 6;

    for (int i = tid; i < NIN * ND; i += 1024) {
        int k = i >> 6;          // 0..128
        int j = i & 63;          // 0..63
        w1p[k][j] = make_float2(W1[j * NIN + k], W1[(j + 64) * NIN + k]);
    }
    for (int i = tid; i < HD * ND; i += 1024) {
        int k = i >> 6;
        int j = i & 63;
        w2t[k][j] = W2[j * HD + k];
    }
    __syncthreads();

    const float rb1a = b1[lane];
    const float rb1b = b1[lane + 64];
    const float rb2  = b2[lane];

    const int gw = blockIdx.x * 16 + w;
    const int nw = gridDim.x * 16;

    for (int q = gw; q < NE / 4; q += nw) {
        const int e0 = q * 4;
        const int s0 = ei[e0 + 0], s1 = ei[e0 + 1], s2 = ei[e0 + 2], s3 = ei[e0 + 3];
        const int d0 = ei[NE + e0 + 0], d1 = ei[NE + e0 + 1],
                  d2 = ei[NE + e0 + 2], d3 = ei[NE + e0 + 3];
        const float a0 = ea[e0 + 0], a1 = ea[e0 + 1], a2 = ea[e0 + 2], a3 = ea[e0 + 3];

        // gather: v = [x_src(64) ; x_dst(64) ; ea(1)], interleaved over 4 edges
        vbuf[w][lane] = make_float4(x[s0 * ND + lane], x[s1 * ND + lane],
                                    x[s2 * ND + lane], x[s3 * ND + lane]);
        vbuf[w][64 + lane] = make_float4(x[d0 * ND + lane], x[d1 * ND + lane],
                                         x[d2 * ND + lane], x[d3 * ND + lane]);
        if (lane == 0) vbuf[w][128] = make_float4(a0, a1, a2, a3);

        // h = relu(W1 @ v + b1): lane j owns h[j] and h[j+64], for 4 edges
        float ha0 = rb1a, ha1 = rb1a, ha2 = rb1a, ha3 = rb1a;
        float hb0 = rb1b, hb1 = rb1b, hb2 = rb1b, hb3 = rb1b;
        #pragma unroll 4
        for (int k = 0; k < NIN; ++k) {
            const float4 v  = vbuf[w][k];     // b128 broadcast
            const float2 wv = w1p[k][lane];   // b64 lane-consecutive
            ha0 = fmaf(wv.x, v.x, ha0);
            ha1 = fmaf(wv.x, v.y, ha1);
            ha2 = fmaf(wv.x, v.z, ha2);
            ha3 = fmaf(wv.x, v.w, ha3);
            hb0 = fmaf(wv.y, v.x, hb0);
            hb1 = fmaf(wv.y, v.y, hb1);
            hb2 = fmaf(wv.y, v.z, hb2);
            hb3 = fmaf(wv.y, v.w, hb3);
        }

        // relu + write h back into the per-wave buffer (wave-synchronous)
        vbuf[w][lane]      = make_float4(fmaxf(ha0, 0.f), fmaxf(ha1, 0.f),
                                         fmaxf(ha2, 0.f), fmaxf(ha3, 0.f));
        vbuf[w][64 + lane] = make_float4(fmaxf(hb0, 0.f), fmaxf(hb1, 0.f),
                                         fmaxf(hb2, 0.f), fmaxf(hb3, 0.f));

        // m = W2 @ h + b2: lane j owns m[j], for 4 edges
        float m0 = rb2, m1 = rb2, m2 = rb2, m3 = rb2;
        #pragma unroll 4
        for (int k = 0; k < HD; ++k) {
            const float4 hv = vbuf[w][k];     // b128 broadcast
            const float  wv = w2t[k][lane];   // b32 lane-consecutive
            m0 = fmaf(wv, hv.x, m0);
            m1 = fmaf(wv, hv.y, m1);
            m2 = fmaf(wv, hv.z, m2);
            m3 = fmaf(wv, hv.w, m3);
        }

        atomicAdd(&aggr[d0 * ND + lane], m0);
        atomicAdd(&aggr[d1 * ND + lane], m1);
        atomicAdd(&aggr[d2 * ND + lane], m2);
        atomicAdd(&aggr[d3 * ND + lane], m3);
    }
}

// ---------------------------------------------------------------------------
// gru_kernel: torch GRUCell(input=aggr, hidden=x) -> out
// 512 threads = 8 waves / block; lane j owns output feature j; 4 nodes / wave.
// ---------------------------------------------------------------------------
__global__ __launch_bounds__(512) void gru_kernel(
    const float* __restrict__ x, const float* __restrict__ aggr,
    const float* __restrict__ Wih, const float* __restrict__ bih,
    const float* __restrict__ Whh, const float* __restrict__ bhh,
    float* __restrict__ out)
{
    // wih4[k][j] = {W_ih[j][k], W_ih[j+64][k], W_ih[j+128][k], 0}  (65536 B each)
    __shared__ float4 wih4[ND][ND];
    __shared__ float4 whh4[ND][ND];
    __shared__ float4 xbuf[8][ND];   // 8192 B
    __shared__ float4 abuf[8][ND];   // 8192 B
    // total LDS: 147456 B

    const int tid  = threadIdx.x;
    const int lane = tid & 63;
    const int w    = tid >> 6;

    for (int i = tid; i < ND * ND; i += 512) {
        int k = i >> 6;
        int j = i & 63;
        wih4[k][j] = make_float4(Wih[j * ND + k], Wih[(j + 64) * ND + k],
                                 Wih[(j + 128) * ND + k], 0.f);
        whh4[k][j] = make_float4(Whh[j * ND + k], Whh[(j + 64) * ND + k],
                                 Whh[(j + 128) * ND + k], 0.f);
    }
    __syncthreads();

    const float bir = bih[lane], biz = bih[lane + 64], bin_ = bih[lane + 128];
    const float bhr = bhh[lane], bhz = bhh[lane + 64], bhn  = bhh[lane + 128];

    const int gw = blockIdx.x * 8 + w;
    const int nw = gridDim.x * 8;

    for (int q = gw; q < NN / 4; q += nw) {
        const int n0 = q * 4;
        float xv[4], av[4];
        #pragma unroll
        for (int e = 0; e < 4; ++e) {
            xv[e] = x[(n0 + e) * ND + lane];
            av[e] = aggr[(n0 + e) * ND + lane];
        }
        xbuf[w][lane] = make_float4(xv[0], xv[1], xv[2], xv[3]);
        abuf[w][lane] = make_float4(av[0], av[1], av[2], av[3]);

        float ir[4], iz[4], in_[4], hr[4], hz[4], hn[4];
        #pragma unroll
        for (int e = 0; e < 4; ++e) {
            ir[e] = bir; iz[e] = biz; in_[e] = bin_;
            hr[e] = bhr; hz[e] = bhz; hn[e] = bhn;
        }

        for (int k = 0; k < ND; ++k) {
            const float4 wi = wih4[k][lane];
            const float4 wh = whh4[k][lane];
            const float4 a4 = abuf[w][k];   // broadcast
            const float4 x4 = xbuf[w][k];   // broadcast
            const float aa[4] = {a4.x, a4.y, a4.z, a4.w};
            const float xx[4] = {x4.x, x4.y, x4.z, x4.w};
            #pragma unroll
            for (int e = 0; e < 4; ++e) {
                ir[e]  = fmaf(wi.x, aa[e], ir[e]);
                iz[e]  = fmaf(wi.y, aa[e], iz[e]);
                in_[e] = fmaf(wi.z, aa[e], in_[e]);
                hr[e]  = fmaf(wh.x, xx[e], hr[e]);
                hz[e]  = fmaf(wh.y, xx[e], hz[e]);
                hn[e]  = fmaf(wh.z, xx[e], hn[e]);
            }
        }

        #pragma unroll
        for (int e = 0; e < 4; ++e) {
            const float r  = 1.f / (1.f + __expf(-(ir[e] + hr[e])));
            const float z  = 1.f / (1.f + __expf(-(iz[e] + hz[e])));
            const float nv = in_[e] + r * hn[e];
            const float n  = 2.f / (1.f + __expf(-2.f * nv)) - 1.f;  // tanh
            out[(n0 + e) * ND + lane] = (1.f - z) * n + z * xv[e];
        }
    }
}

extern "C" void kernel_launch(void* const* d_in, const int* in_sizes, int n_in,
                              void* d_out, int out_size, void* d_ws, size_t ws_size,
                              hipStream_t stream) {
    const float* x   = (const float*)d_in[0];
    const int*   ei  = (const int*)d_in[1];
    const float* ea  = (const float*)d_in[2];
    const float* W1  = (const float*)d_in[3];
    const float* b1  = (const float*)d_in[4];
    const float* W2  = (const float*)d_in[5];
    const float* b2  = (const float*)d_in[6];
    const float* Wih = (const float*)d_in[7];
    const float* bih = (const float*)d_in[8];
    const float* Whh = (const float*)d_in[9];
    const float* bhh = (const float*)d_in[10];
    float* out  = (float*)d_out;
    float* aggr = (float*)d_ws;   // N*ND floats = 25.6 MB scratch

    hipMemsetAsync(aggr, 0, (size_t)NN * ND * sizeof(float), stream);
    hipLaunchKernelGGL(msg_kernel, dim3(256), dim3(1024), 0, stream,
                       x, ei, ea, W1, b1, W2, b2, aggr);
    hipLaunchKernelGGL(gru_kernel, dim3(256), dim3(512), 0, stream,
                       x, aggr, Wih, bih, Whh, bhh, out);
}

// Round 2
// 1046.525 us; speedup vs baseline: 1.6105x; 1.6105x over previous
//
#include <hip/hip_runtime.h>

#define NN 100000
#define NE 1600000
#define ND 64
#define HD 128

typedef float f32x4 __attribute__((ext_vector_type(4)));
typedef short s16x8 __attribute__((ext_vector_type(8)));

// round-to-nearest-even fp32 -> bf16 (as raw short)
static __device__ __forceinline__ short f2bf(float f) {
    union { float f; unsigned u; } v; v.f = f;
    unsigned r = (v.u + 0x7fffu + ((v.u >> 16) & 1u)) >> 16;
    return (short)r;
}

// swizzled LDS index for weight/act tiles: row n (n&15 used), col k in [0,128)
// 16B chunks XORed by (n&15) -> conflict-free b128 reads across 16 n-rows
#define LSW(n, k) (((n) << 7) + ((((k) >> 3) ^ ((n) & 15)) << 3) + ((k) & 7))

// ---------------------------------------------------------------------------
// msg_mfma: per-edge MLP on MFMA. 512 thr = 8 waves/block; wave = 16 edges/iter.
//   h[16x128] = V[16x129] @ W1^T   (K=128 via 4 MFMA steps; k=128 = ea rank-1)
//   m[16x64]  = relu(h) @ W2^T     (K=128 via 4 MFMA steps)
// then atomicAdd into aggr[dst].
// LDS: W1b 32KB + W2b 16KB + per-wave h-buf 8*4KB = 80KB -> 2 blocks/CU.
// ---------------------------------------------------------------------------
__global__ __launch_bounds__(512) void msg_mfma(
    const float* __restrict__ x, const int* __restrict__ ei,
    const float* __restrict__ ea, const float* __restrict__ W1,
    const float* __restrict__ b1, const float* __restrict__ W2,
    const float* __restrict__ b2, float* __restrict__ aggr)
{
    __shared__ short w1lds[128 * 128];   // [n][k] bf16, swizzled
    __shared__ short w2lds[64 * 128];    // [n][k] bf16, swizzled
    __shared__ short vbuf[8 * 16 * 128]; // per-wave relu(h) [m][k] bf16, swizzled

    const int tid = threadIdx.x;

    // stage weights (fp32 global -> bf16 LDS, swizzled)
    for (int i = tid; i < 128 * 128; i += 512) {
        int n = i >> 7, k = i & 127;
        w1lds[LSW(n, k)] = f2bf(W1[n * 129 + k]);
    }
    for (int i = tid; i < 64 * 128; i += 512) {
        int n = i >> 7, k = i & 127;
        w2lds[LSW(n, k)] = f2bf(W2[n * 128 + k]);
    }
    __syncthreads();

    const int lane = tid & 63;
    const int w    = tid >> 6;
    const int nlo  = lane & 15;   // n / m within tile
    const int q    = lane >> 4;   // quad group

    // loop-invariant per-lane weights: ea column of W1, biases
    float w1l[8], b1v[8], b2v[4];
    #pragma unroll
    for (int t = 0; t < 8; ++t) {
        w1l[t] = W1[(nlo + 16 * t) * 129 + 128];
        b1v[t] = b1[nlo + 16 * t];
    }
    #pragma unroll
    for (int t = 0; t < 4; ++t) b2v[t] = b2[nlo + 16 * t];

    short* myv = vbuf + w * (16 * 128);

    const int gw = blockIdx.x * 8 + w;
    const int nw = gridDim.x * 8;

    for (int it = gw; it < NE / 16; it += nw) {
        const int e0 = it * 16;
        const int sv = ei[e0 + nlo];            // src row for edge (nlo)
        const int dv = ei[NE + e0 + nlo];       // dst row for edge (nlo)
        const float4 eav = *(const float4*)(ea + e0 + q * 4); // ea for edges q*4..q*4+3

        // ---- GEMM1: h = V @ W1^T + b1 ----
        f32x4 acc[8];
        #pragma unroll
        for (int t = 0; t < 8; ++t) { acc[t][0] = b1v[t]; acc[t][1] = b1v[t]; acc[t][2] = b1v[t]; acc[t][3] = b1v[t]; }

        #pragma unroll
        for (int kk = 0; kk < 4; ++kk) {
            const size_t row = (size_t)((kk < 2) ? sv : dv);
            const int col = ((kk & 1) << 5) + (q << 3);          // 8 consecutive cols
            const float4* xp = (const float4*)(x + row * ND + col);
            const float4 fa = xp[0], fb = xp[1];
            s16x8 af;
            af[0] = f2bf(fa.x); af[1] = f2bf(fa.y); af[2] = f2bf(fa.z); af[3] = f2bf(fa.w);
            af[4] = f2bf(fb.x); af[5] = f2bf(fb.y); af[6] = f2bf(fb.z); af[7] = f2bf(fb.w);
            const int chunk = ((kk * 4 + q) ^ nlo) << 3;
            #pragma unroll
            for (int t = 0; t < 8; ++t) {
                const s16x8 bf = *(const s16x8*)(w1lds + ((nlo + 16 * t) << 7) + chunk);
                acc[t] = __builtin_amdgcn_mfma_f32_16x16x32_bf16(af, bf, acc[t], 0, 0, 0);
            }
        }

        // ---- epilogue1: + ea * w1[:,128], relu, -> bf16, transpose via LDS ----
        const float ear[4] = {eav.x, eav.y, eav.z, eav.w};
        #pragma unroll
        for (int t = 0; t < 8; ++t) {
            #pragma unroll
            for (int r = 0; r < 4; ++r) {
                const float hv = fmaxf(acc[t][r] + ear[r] * w1l[t], 0.f);
                const int m = q * 4 + r;          // edge row in tile
                const int k = nlo + 16 * t;       // hidden index
                myv[LSW(m, k)] = f2bf(hv);
            }
        }

        // ---- GEMM2: m = relu(h) @ W2^T + b2 ----
        f32x4 acc2[4];
        #pragma unroll
        for (int t = 0; t < 4; ++t) { acc2[t][0] = b2v[t]; acc2[t][1] = b2v[t]; acc2[t][2] = b2v[t]; acc2[t][3] = b2v[t]; }

        #pragma unroll
        for (int kk = 0; kk < 4; ++kk) {
            const int chunk = ((kk * 4 + q) ^ nlo) << 3;
            const s16x8 af = *(const s16x8*)(myv + (nlo << 7) + chunk);
            #pragma unroll
            for (int t = 0; t < 4; ++t) {
                const s16x8 bf = *(const s16x8*)(w2lds + ((nlo + 16 * t) << 7) + chunk);
                acc2[t] = __builtin_amdgcn_mfma_f32_16x16x32_bf16(af, bf, acc2[t], 0, 0, 0);
            }
        }

        // ---- scatter: atomicAdd(aggr[dst[m]][n]) ----
        #pragma unroll
        for (int r = 0; r < 4; ++r) {
            const int dd = __shfl(dv, q * 4 + r, 64);   // dst of edge row m=q*4+r
            float* ap = aggr + (size_t)dd * ND + nlo;
            #pragma unroll
            for (int t = 0; t < 4; ++t)
                atomicAdd(ap + 16 * t, acc2[t][r]);
        }
    }
}

// ---------------------------------------------------------------------------
// gru_kernel: torch GRUCell(input=aggr, hidden=x) -> out  (unchanged fp32)
// ---------------------------------------------------------------------------
__global__ __launch_bounds__(512) void gru_kernel(
    const float* __restrict__ x, const float* __restrict__ aggr,
    const float* __restrict__ Wih, const float* __restrict__ bih,
    const float* __restrict__ Whh, const float* __restrict__ bhh,
    float* __restrict__ out)
{
    __shared__ float4 wih4[ND][ND];
    __shared__ float4 whh4[ND][ND];
    __shared__ float4 xbuf[8][ND];
    __shared__ float4 abuf[8][ND];

    const int tid  = threadIdx.x;
    const int lane = tid & 63;
    const int w    = tid >> 6;

    for (int i = tid; i < ND * ND; i += 512) {
        int k = i >> 6;
        int j = i & 63;
        wih4[k][j] = make_float4(Wih[j * ND + k], Wih[(j + 64) * ND + k],
                                 Wih[(j + 128) * ND + k], 0.f);
        whh4[k][j] = make_float4(Whh[j * ND + k], Whh[(j + 64) * ND + k],
                                 Whh[(j + 128) * ND + k], 0.f);
    }
    __syncthreads();

    const float bir = bih[lane], biz = bih[lane + 64], bin_ = bih[lane + 128];
    const float bhr = bhh[lane], bhz = bhh[lane + 64], bhn  = bhh[lane + 128];

    const int gw = blockIdx.x * 8 + w;
    const int nw = gridDim.x * 8;

    for (int qd = gw; qd < NN / 4; qd += nw) {
        const int n0 = qd * 4;
        float xv[4], av[4];
        #pragma unroll
        for (int e = 0; e < 4; ++e) {
            xv[e] = x[(n0 + e) * ND + lane];
            av[e] = aggr[(n0 + e) * ND + lane];
        }
        xbuf[w][lane] = make_float4(xv[0], xv[1], xv[2], xv[3]);
        abuf[w][lane] = make_float4(av[0], av[1], av[2], av[3]);

        float ir[4], iz[4], in_[4], hr[4], hz[4], hn[4];
        #pragma unroll
        for (int e = 0; e < 4; ++e) {
            ir[e] = bir; iz[e] = biz; in_[e] = bin_;
            hr[e] = bhr; hz[e] = bhz; hn[e] = bhn;
        }

        for (int k = 0; k < ND; ++k) {
            const float4 wi = wih4[k][lane];
            const float4 wh = whh4[k][lane];
            const float4 a4 = abuf[w][k];
            const float4 x4 = xbuf[w][k];
            const float aa[4] = {a4.x, a4.y, a4.z, a4.w};
            const float xx[4] = {x4.x, x4.y, x4.z, x4.w};
            #pragma unroll
            for (int e = 0; e < 4; ++e) {
                ir[e]  = fmaf(wi.x, aa[e], ir[e]);
                iz[e]  = fmaf(wi.y, aa[e], iz[e]);
                in_[e] = fmaf(wi.z, aa[e], in_[e]);
                hr[e]  = fmaf(wh.x, xx[e], hr[e]);
                hz[e]  = fmaf(wh.y, xx[e], hz[e]);
                hn[e]  = fmaf(wh.z, xx[e], hn[e]);
            }
        }

        #pragma unroll
        for (int e = 0; e < 4; ++e) {
            const float r  = 1.f / (1.f + __expf(-(ir[e] + hr[e])));
            const float z  = 1.f / (1.f + __expf(-(iz[e] + hz[e])));
            const float nv = in_[e] + r * hn[e];
            const float n  = 2.f / (1.f + __expf(-2.f * nv)) - 1.f;  // tanh
            out[(n0 + e) * ND + lane] = (1.f - z) * n + z * xv[e];
        }
    }
}

extern "C" void kernel_launch(void* const* d_in, const int* in_sizes, int n_in,
                              void* d_out, int out_size, void* d_ws, size_t ws_size,
                              hipStream_t stream) {
    const float* x   = (const float*)d_in[0];
    const int*   ei  = (const int*)d_in[1];
    const float* ea  = (const float*)d_in[2];
    const float* W1  = (const float*)d_in[3];
    const float* b1  = (const float*)d_in[4];
    const float* W2  = (const float*)d_in[5];
    const float* b2  = (const float*)d_in[6];
    const float* Wih = (const float*)d_in[7];
    const float* bih = (const float*)d_in[8];
    const float* Whh = (const float*)d_in[9];
    const float* bhh = (const float*)d_in[10];
    float* out  = (float*)d_out;
    float* aggr = (float*)d_ws;   // N*ND floats = 25.6 MB scratch

    hipMemsetAsync(aggr, 0, (size_t)NN * ND * sizeof(float), stream);
    hipLaunchKernelGGL(msg_mfma, dim3(512), dim3(512), 0, stream,
                       x, ei, ea, W1, b1, W2, b2, aggr);
    hipLaunchKernelGGL(gru_kernel, dim3(256), dim3(512), 0, stream,
                       x, aggr, Wih, bih, Whh, bhh, out);
}

// Round 3
// 753.566 us; speedup vs baseline: 2.2366x; 1.3888x over previous
//
#include <hip/hip_runtime.h>

#define NN 100000
#define NE 1600000
#define ND 64
#define HD 128
#define NSL 8          // dst slices (one per XCD)
#define SLN 12500      // nodes per slice
#define NB 256         // bucketing blocks
#define CH 6250        // edges per bucketing block (NE/NB)

typedef float f32x4 __attribute__((ext_vector_type(4)));
typedef short s16x8 __attribute__((ext_vector_type(8)));

// round-to-nearest-even fp32 -> bf16 (raw short)
static __device__ __forceinline__ short f2bf(float f) {
    union { float f; unsigned u; } v; v.f = f;
    unsigned r = (v.u + 0x7fffu + ((v.u >> 16) & 1u)) >> 16;
    return (short)r;
}

// swizzled LDS index, 128-col tiles (16B chunk ^ row) -> conflict-free b128
#define LSW(n, k)  (((n) << 7) + ((((k) >> 3) ^ ((n) & 15)) << 3) + ((k) & 7))
// swizzled LDS index, 64-col tiles
#define LSW64(n, k) (((n) << 6) + ((((k) >> 3) ^ ((n) & 7)) << 3) + ((k) & 7))

// ---------------------------------------------------------------------------
// conv_bf16: x fp32 -> xb bf16 (once per call; gathers then read 128B rows)
// ---------------------------------------------------------------------------
__global__ __launch_bounds__(256) void conv_bf16(const float* __restrict__ x,
                                                 short* __restrict__ xb) {
    const int NG = NN * ND / 8;   // 800000 groups of 8
    for (int g = blockIdx.x * 256 + threadIdx.x; g < NG; g += gridDim.x * 256) {
        const float4 a = ((const float4*)x)[g * 2];
        const float4 b = ((const float4*)x)[g * 2 + 1];
        s16x8 o;
        o[0] = f2bf(a.x); o[1] = f2bf(a.y); o[2] = f2bf(a.z); o[3] = f2bf(a.w);
        o[4] = f2bf(b.x); o[5] = f2bf(b.y); o[6] = f2bf(b.z); o[7] = f2bf(b.w);
        ((s16x8*)xb)[g] = o;
    }
}

// ---------------------------------------------------------------------------
// bucketing: per-block 8-bin histogram -> scan -> stable-ish scatter
// gHist/gBase layout: [slice][block]  (flat index s*NB + b)
// ---------------------------------------------------------------------------
__global__ __launch_bounds__(1024) void hist_kernel(const int* __restrict__ ei,
                                                    int* __restrict__ gHist) {
    __shared__ int h[NSL];
    const int tid = threadIdx.x;
    if (tid < NSL) h[tid] = 0;
    __syncthreads();
    const int base = blockIdx.x * CH;
    for (int i = tid; i < CH; i += 1024)
        atomicAdd(&h[ei[NE + base + i] / SLN], 1);
    __syncthreads();
    if (tid < NSL) gHist[tid * NB + blockIdx.x] = h[tid];
}

__global__ __launch_bounds__(1024) void scan_kernel(const int* __restrict__ gHist,
                                                    int* __restrict__ gBase,
                                                    int* __restrict__ sliceStart) {
    __shared__ int A[1024], B[1024];
    const int t = threadIdx.x;
    const int v0 = gHist[2 * t], v1 = gHist[2 * t + 1];
    A[t] = v0 + v1;
    __syncthreads();
    int* src = A; int* dst = B;
    for (int off = 1; off < 1024; off <<= 1) {
        int val = src[t];
        if (t >= off) val += src[t - off];
        dst[t] = val;
        __syncthreads();
        int* tmp = src; src = dst; dst = tmp;
    }
    const int excl = t ? src[t - 1] : 0;      // exclusive over pair t
    gBase[2 * t]     = excl;
    gBase[2 * t + 1] = excl + v0;
    if (t < 9) sliceStart[t] = (t == 0) ? 0 : ((t == 8) ? NE : src[t * 128 - 1]);
}

__global__ __launch_bounds__(1024) void scatter_kernel(
    const int* __restrict__ ei, const float* __restrict__ ea,
    const int* __restrict__ gBase, int* __restrict__ rsrc,
    int* __restrict__ rdst, float* __restrict__ rea) {
    __shared__ int cur[NSL];
    const int tid = threadIdx.x;
    if (tid < NSL) cur[tid] = gBase[tid * NB + blockIdx.x];
    __syncthreads();
    const int base = blockIdx.x * CH;
    for (int i = tid; i < CH; i += 1024) {
        const int e = base + i;
        const int sv = ei[e], d = ei[NE + e];
        const float av = ea[e];
        const int pos = atomicAdd(&cur[d / SLN], 1);
        rsrc[pos] = sv; rdst[pos] = d; rea[pos] = av;
    }
}

// ---------------------------------------------------------------------------
// msg_mfma2: per-edge MLP on MFMA over slice-bucketed edges.
// slice = blockIdx%8 (XCD heuristic) -> aggr slice (3.2MB) + dst rows (1.6MB)
// stay L2-resident; src gather from bf16 xb (12.8MB, L3-resident).
// ---------------------------------------------------------------------------
__global__ __launch_bounds__(512) void msg_mfma2(
    const short* __restrict__ xb, const int* __restrict__ rsrc,
    const int* __restrict__ rdst, const float* __restrict__ rea,
    const int* __restrict__ sliceStart,
    const float* __restrict__ W1, const float* __restrict__ b1,
    const float* __restrict__ W2, const float* __restrict__ b2,
    float* __restrict__ aggr)
{
    __shared__ short w1lds[128 * 128];
    __shared__ short w2lds[64 * 128];
    __shared__ short vbuf[8 * 16 * 128];

    const int tid = threadIdx.x;
    for (int i = tid; i < 128 * 128; i += 512) {
        int n = i >> 7, k = i & 127;
        w1lds[LSW(n, k)] = f2bf(W1[n * 129 + k]);
    }
    for (int i = tid; i < 64 * 128; i += 512) {
        int n = i >> 7, k = i & 127;
        w2lds[LSW(n, k)] = f2bf(W2[n * 128 + k]);
    }
    __syncthreads();

    const int lane = tid & 63;
    const int w    = tid >> 6;
    const int nlo  = lane & 15;
    const int q    = lane >> 4;

    float w1l[8], b1v[8], b2v[4];
    #pragma unroll
    for (int t = 0; t < 8; ++t) {
        w1l[t] = W1[(nlo + 16 * t) * 129 + 128];
        b1v[t] = b1[nlo + 16 * t];
    }
    #pragma unroll
    for (int t = 0; t < 4; ++t) b2v[t] = b2[nlo + 16 * t];

    short* myv = vbuf + w * (16 * 128);

    const int s     = blockIdx.x & 7;
    const int start = sliceStart[s], end = sliceStart[s + 1];
    const int tIdx  = (blockIdx.x >> 3) * 8 + w;
    const int tStr  = (gridDim.x >> 3) * 8;

    for (int p = start + tIdx * 16; p < end; p += tStr * 16) {
        const int idx = min(p + nlo, end - 1);   // clamp slice tail
        const int sv  = rsrc[idx];
        const int dv  = rdst[idx];
        const float eav = rea[idx];

        // ---- GEMM1: h = [x_src;x_dst] @ W1^T + b1 ----
        f32x4 acc[8];
        #pragma unroll
        for (int t = 0; t < 8; ++t) { acc[t][0] = b1v[t]; acc[t][1] = b1v[t]; acc[t][2] = b1v[t]; acc[t][3] = b1v[t]; }

        #pragma unroll
        for (int kk = 0; kk < 4; ++kk) {
            const int row = (kk < 2) ? sv : dv;
            const s16x8 af = *(const s16x8*)(xb + row * ND + ((kk & 1) << 5) + (q << 3));
            const int chunk = ((kk * 4 + q) ^ nlo) << 3;
            #pragma unroll
            for (int t = 0; t < 8; ++t) {
                const s16x8 bf = *(const s16x8*)(w1lds + ((nlo + 16 * t) << 7) + chunk);
                acc[t] = __builtin_amdgcn_mfma_f32_16x16x32_bf16(af, bf, acc[t], 0, 0, 0);
            }
        }

        // ---- epilogue1: + ea * W1[:,128], relu, bf16, transpose via LDS ----
        float ear[4];
        #pragma unroll
        for (int r = 0; r < 4; ++r) ear[r] = __shfl(eav, q * 4 + r, 64);
        #pragma unroll
        for (int t = 0; t < 8; ++t) {
            #pragma unroll
            for (int r = 0; r < 4; ++r) {
                const float hv = fmaxf(acc[t][r] + ear[r] * w1l[t], 0.f);
                const int m = q * 4 + r;
                const int k = nlo + 16 * t;
                myv[LSW(m, k)] = f2bf(hv);
            }
        }

        // ---- GEMM2: m = relu(h) @ W2^T + b2 ----
        f32x4 acc2[4];
        #pragma unroll
        for (int t = 0; t < 4; ++t) { acc2[t][0] = b2v[t]; acc2[t][1] = b2v[t]; acc2[t][2] = b2v[t]; acc2[t][3] = b2v[t]; }

        #pragma unroll
        for (int kk = 0; kk < 4; ++kk) {
            const int chunk = ((kk * 4 + q) ^ nlo) << 3;
            const s16x8 af = *(const s16x8*)(myv + (nlo << 7) + chunk);
            #pragma unroll
            for (int t = 0; t < 4; ++t) {
                const s16x8 bf = *(const s16x8*)(w2lds + ((nlo + 16 * t) << 7) + chunk);
                acc2[t] = __builtin_amdgcn_mfma_f32_16x16x32_bf16(af, bf, acc2[t], 0, 0, 0);
            }
        }

        // ---- scatter: atomics now L2-resident (slice-local) ----
        #pragma unroll
        for (int r = 0; r < 4; ++r) {
            const int m  = q * 4 + r;
            const int dd = __shfl(dv, m, 64);
            if (p + m < end) {
                float* ap = aggr + dd * ND + nlo;
                atomicAdd(ap +  0, acc2[0][r]);
                atomicAdd(ap + 16, acc2[1][r]);
                atomicAdd(ap + 32, acc2[2][r]);
                atomicAdd(ap + 48, acc2[3][r]);
            }
        }
    }
}

// ---------------------------------------------------------------------------
// gru_mfma: GRUCell on MFMA. wave = 16 nodes; 2 GEMMs [16x64]@[64x192] bf16.
// ---------------------------------------------------------------------------
__global__ __launch_bounds__(512) void gru_mfma(
    const float* __restrict__ x, const float* __restrict__ aggr,
    const float* __restrict__ Wih, const float* __restrict__ bih,
    const float* __restrict__ Whh, const float* __restrict__ bhh,
    float* __restrict__ out)
{
    __shared__ short wi[192 * 64];
    __shared__ short wh[192 * 64];

    const int tid = threadIdx.x;
    for (int i = tid; i < 192 * 64; i += 512) {
        int n = i >> 6, k = i & 63;
        wi[LSW64(n, k)] = f2bf(Wih[n * 64 + k]);
        wh[LSW64(n, k)] = f2bf(Whh[n * 64 + k]);
    }
    __syncthreads();

    const int lane = tid & 63;
    const int w    = tid >> 6;
    const int nlo  = lane & 15;
    const int q    = lane >> 4;

    float bi[12], bh[12];
    #pragma unroll
    for (int t = 0; t < 12; ++t) { bi[t] = bih[16 * t + nlo]; bh[t] = bhh[16 * t + nlo]; }

    const int gw = blockIdx.x * 8 + w;
    const int nw = gridDim.x * 8;

    for (int tile = gw; tile < NN / 16; tile += nw) {
        const int n0 = tile * 16;
        f32x4 ai[12], ah[12];
        #pragma unroll
        for (int t = 0; t < 12; ++t) {
            ai[t][0] = bi[t]; ai[t][1] = bi[t]; ai[t][2] = bi[t]; ai[t][3] = bi[t];
            ah[t][0] = bh[t]; ah[t][1] = bh[t]; ah[t][2] = bh[t]; ah[t][3] = bh[t];
        }

        #pragma unroll
        for (int kk = 0; kk < 2; ++kk) {
            const int coff = (n0 + nlo) * ND + kk * 32 + q * 8;
            const float4 a0 = *(const float4*)(aggr + coff);
            const float4 a1 = *(const float4*)(aggr + coff + 4);
            const float4 x0 = *(const float4*)(x + coff);
            const float4 x1 = *(const float4*)(x + coff + 4);
            s16x8 fA, fX;
            fA[0] = f2bf(a0.x); fA[1] = f2bf(a0.y); fA[2] = f2bf(a0.z); fA[3] = f2bf(a0.w);
            fA[4] = f2bf(a1.x); fA[5] = f2bf(a1.y); fA[6] = f2bf(a1.z); fA[7] = f2bf(a1.w);
            fX[0] = f2bf(x0.x); fX[1] = f2bf(x0.y); fX[2] = f2bf(x0.z); fX[3] = f2bf(x0.w);
            fX[4] = f2bf(x1.x); fX[5] = f2bf(x1.y); fX[6] = f2bf(x1.z); fX[7] = f2bf(x1.w);
            const int chunk = kk * 4 + q;
            #pragma unroll
            for (int t = 0; t < 12; ++t) {
                const int rb = 16 * t + nlo;
                const int boff = (rb << 6) + (((chunk) ^ (rb & 7)) << 3);
                const s16x8 bI = *(const s16x8*)(wi + boff);
                const s16x8 bH = *(const s16x8*)(wh + boff);
                ai[t] = __builtin_amdgcn_mfma_f32_16x16x32_bf16(fA, bI, ai[t], 0, 0, 0);
                ah[t] = __builtin_amdgcn_mfma_f32_16x16x32_bf16(fX, bH, ah[t], 0, 0, 0);
            }
        }

        #pragma unroll
        for (int t = 0; t < 4; ++t) {
            #pragma unroll
            for (int r = 0; r < 4; ++r) {
                const int node = n0 + q * 4 + r;
                const int c    = nlo + 16 * t;
                const float rr = 1.f / (1.f + __expf(-(ai[t][r] + ah[t][r])));
                const float zz = 1.f / (1.f + __expf(-(ai[t + 4][r] + ah[t + 4][r])));
                const float nv = ai[t + 8][r] + rr * ah[t + 8][r];
                const float nn = 2.f / (1.f + __expf(-2.f * nv)) - 1.f;   // tanh
                const float xv = x[node * ND + c];
                out[node * ND + c] = (1.f - zz) * nn + zz * xv;
            }
        }
    }
}

extern "C" void kernel_launch(void* const* d_in, const int* in_sizes, int n_in,
                              void* d_out, int out_size, void* d_ws, size_t ws_size,
                              hipStream_t stream) {
    const float* x   = (const float*)d_in[0];
    const int*   ei  = (const int*)d_in[1];
    const float* ea  = (const float*)d_in[2];
    const float* W1  = (const float*)d_in[3];
    const float* b1  = (const float*)d_in[4];
    const float* W2  = (const float*)d_in[5];
    const float* b2  = (const float*)d_in[6];
    const float* Wih = (const float*)d_in[7];
    const float* bih = (const float*)d_in[8];
    const float* Whh = (const float*)d_in[9];
    const float* bhh = (const float*)d_in[10];
    float* out = (float*)d_out;

    // workspace layout (~57.7 MB)
    char* ws = (char*)d_ws;
    float* aggr       = (float*)(ws);                    // 25,600,000 B
    short* xb         = (short*)(ws + 25600000);         // 12,800,000 B
    int*   rsrc       = (int*)  (ws + 38400000);         //  6,400,000 B
    int*   rdst       = (int*)  (ws + 44800000);         //  6,400,000 B
    float* rea        = (float*)(ws + 51200000);         //  6,400,000 B
    int*   gHist      = (int*)  (ws + 57600000);         //      8,192 B
    int*   gBase      = (int*)  (ws + 57608192);         //      8,192 B
    int*   sliceStart = (int*)  (ws + 57616384);         //         36 B

    hipMemsetAsync(aggr, 0, (size_t)NN * ND * sizeof(float), stream);
    hipMemsetAsync(gHist, 0, NSL * NB * sizeof(int), stream);

    hipLaunchKernelGGL(conv_bf16, dim3(512), dim3(256), 0, stream, x, xb);
    hipLaunchKernelGGL(hist_kernel, dim3(NB), dim3(1024), 0, stream, ei, gHist);
    hipLaunchKernelGGL(scan_kernel, dim3(1), dim3(1024), 0, stream,
                       gHist, gBase, sliceStart);
    hipLaunchKernelGGL(scatter_kernel, dim3(NB), dim3(1024), 0, stream,
                       ei, ea, gBase, rsrc, rdst, rea);
    hipLaunchKernelGGL(msg_mfma2, dim3(512), dim3(512), 0, stream,
                       xb, rsrc, rdst, rea, sliceStart, W1, b1, W2, b2, aggr);
    hipLaunchKernelGGL(gru_mfma, dim3(256), dim3(512), 0, stream,
                       x, aggr, Wih, bih, Whh, bhh, out);
}